// Round 17
// baseline (93.047 us; speedup 1.0000x reference)
//
#include <hip/hip_runtime.h>
#include <math.h>

#define NN 50000
#define RR 8
#define EE 100000
#define BB 16384
#define ET 800000
#define NB 98                 // coarse buckets per relation (512 nodes each)
#define CAP 2048              // region stride in edges (stored cnt <= 2047)
#define OVFCAP 1024

typedef unsigned int uint;
typedef unsigned short ushort;
typedef __attribute__((ext_vector_type(4))) float f32x4;
typedef _Float16 f16x8 __attribute__((ext_vector_type(8)));

// pay4[pos]: (col<<16 | val_fp16), grouped by (r, node) per CSR.
// csr[r*NN+n] = (absStart << 11) | deg. nodeList[0..nodeCnt): referenced nodes (dedup).
// slotHead[n]/slotNext[slot]: node -> slots inverse lists. slotUidx[slot] = Ud row index.
// Ud: 8 planes [32768 rows][128] fp16, row i = U_r(nodeList[i]); only nodeCnt rows/plane touched.
// Wfrag: [slot(9)][hi/lo][nfg(8)][ks(4)][lane(64)][8 f16]

// ========== scatterK: round 12 + slot inverse-lists (measured cheap) ==========
__global__ __launch_bounds__(256) void scatterK(
    const float* __restrict__ emb, const float* __restrict__ rel_k, const float* __restrict__ self_k,
    const int* __restrict__ head_idx, const int* __restrict__ tail_idx,
    const int* __restrict__ adj_rows, const int* __restrict__ adj_cols, const float* __restrict__ adj_vals,
    uint* __restrict__ cursor, uint* __restrict__ ovfcnt, uint* __restrict__ ovflist,
    uint2* __restrict__ gpart, int* __restrict__ slotHead, int* __restrict__ slotNext,
    ushort* __restrict__ emb16, ushort* __restrict__ Wfrag)
{
    __shared__ int  srow[2000];
    __shared__ int  hist[NB];
    __shared__ uint lbase[NB];
    const int tid = threadIdx.x, bid = blockIdx.x;

    // ---- node->slot inverse lists: 32K atomicExch total ----
    {
        int g = bid * 256 + tid;
        if (g < 2 * BB) {
            int n = (g < BB) ? head_idx[g] : tail_idx[g - BB];
            slotNext[g] = atomicExch(&slotHead[n], g);
        }
    }

    if (bid < 400) {
        const int r  = bid / 50;
        const int e0 = bid * 2000;
        for (int k = tid; k < NB; k += 256) hist[k] = 0;
        __syncthreads();
        for (int i = tid; i < 2000; i += 256) {
            int n = adj_rows[e0 + i];
            srow[i] = n;
            atomicAdd(&hist[n >> 9], 1);
        }
        __syncthreads();
        if (tid < NB) {
            int h = hist[tid];
            lbase[tid] = h ? atomicAdd(&cursor[r * NB + tid], (uint)h) : 0u;
        }
        __syncthreads();
        for (int i = tid; i < 2000; i += 256) {
            int n = srow[i];
            int c = n >> 9;
            uint prel = atomicAdd(&lbase[c], 1u);
            int e = e0 + i;
            ushort v16 = __builtin_bit_cast(ushort, (_Float16)adj_vals[e]);
            uint pay = ((uint)adj_cols[e] << 16) | (uint)v16;
            if (prel < (uint)(CAP - 1)) {
                gpart[(size_t)(r * NB + c) * CAP + prel] = make_uint2(pay, (uint)n);
            } else {
                uint o = atomicAdd(ovfcnt, 1u);
                if (o < OVFCAP) ovflist[o] = (uint)e;
            }
        }
    } else if (bid < 791) {
        int b = bid - 400;
        #pragma unroll
        for (int i = 0; i < 16; i++) {
            int c = i * 256 + tid;
            int row = b * 128 + (c >> 5);
            if (row < NN) {
                int k4 = (c & 31) * 4;
                float4 v = *(const float4*)(emb + (size_t)row * 128 + k4);
                _Float16 h4[4] = {(_Float16)v.x, (_Float16)v.y, (_Float16)v.z, (_Float16)v.w};
                *(ulonglong1*)(emb16 + (size_t)row * 128 + k4) = *(ulonglong1*)h4;
            }
        }
    } else {
        int r = bid - 791;
        const float* src = (r < RR) ? rel_k + (size_t)r * 128 * 128 : self_k;
        #pragma unroll
        for (int q = 0; q < 8; q++) {
            int ls = q * 256 + tid;
            int nfg = ls >> 8, ks = (ls >> 6) & 3, lane = ls & 63;
            int n = nfg * 16 + (lane & 15);
            int k0 = ks * 32 + (lane >> 4) * 8;
            f16x8 hi, lo;
            #pragma unroll
            for (int j = 0; j < 8; j++) {
                float x = src[(size_t)(k0 + j) * 128 + n];
                _Float16 h = (_Float16)x;
                hi[j] = h;
                lo[j] = (_Float16)(x - (float)h);
            }
            size_t bo = (size_t)(r * 2) * 16384 + (size_t)(nfg * 4 + ks) * 512 + (size_t)lane * 8;
            *(f16x8*)(Wfrag + bo)         = hi;
            *(f16x8*)(Wfrag + 16384 + bo) = lo;
        }
    }
}

// ========== groupK: round 16 counting-sort + referenced-node compaction (r==0 blocks) ==========
__global__ __launch_bounds__(256) void groupK(
    const uint* __restrict__ cursor, const uint2* __restrict__ gpart,
    const int* __restrict__ slotHead,
    uint* __restrict__ pay4, uint* __restrict__ csr,
    int* __restrict__ nodeCnt, int* __restrict__ nodeList)
{
    __shared__ ushort skey[CAP];
    __shared__ uint   spin[CAP];
    __shared__ uint   ssort[CAP];
    __shared__ int    cnt2[512];
    __shared__ int    sa[512], sb[512];
    __shared__ int    cur2[512];
    __shared__ int    lref[512];
    __shared__ int    lcnt, lbase2;
    const int tid = threadIdx.x, rc = blockIdx.x;
    const int c = rc % NB, r = rc / NB;
    const int nodes0 = c * 512;
    const int nnodes = (c == NB - 1) ? (NN - nodes0) : 512;
    uint cntv = cursor[rc]; if (cntv > (uint)(CAP - 1)) cntv = CAP - 1;
    const int cnt = (int)cntv;

    if (tid == 0) lcnt = 0;
    for (int k = tid; k < 512; k += 256) cnt2[k] = 0;
    __syncthreads();
    for (int i = tid; i < cnt; i += 256) {
        uint2 p = gpart[(size_t)rc * CAP + i];
        int key = (int)p.y - nodes0;
        skey[i] = (ushort)key;
        spin[i] = p.x;
        atomicAdd(&cnt2[key], 1);
    }
    __syncthreads();
    for (int k = tid; k < 512; k += 256) sa[k] = cnt2[k];
    __syncthreads();
    int* src = sa; int* dst = sb;
    for (int d = 1; d < 512; d <<= 1) {
        for (int k = tid; k < 512; k += 256)
            dst[k] = src[k] + (k >= d ? src[k - d] : 0);
        __syncthreads();
        int* t = src; src = dst; dst = t;
    }
    for (int k = tid; k < 512; k += 256) cur2[k] = k ? src[k - 1] : 0;
    __syncthreads();
    for (int i = tid; i < cnt; i += 256) {
        int p = atomicAdd(&cur2[skey[i]], 1);
        ssort[p] = spin[i];
    }
    __syncthreads();
    for (int i = tid; i < cnt; i += 256)
        pay4[(size_t)rc * CAP + i] = ssort[i];
    for (int j = tid; j < nnodes; j += 256) {
        uint start = (uint)rc * CAP + (uint)(j ? src[j - 1] : 0);
        csr[r * NN + nodes0 + j] = (start << 11) | (uint)cnt2[j];
    }

    // ---- referenced-node compaction (only relation-0 blocks; node set is r-independent) ----
    if (r == 0) {
        for (int j = tid; j < nnodes; j += 256)
            if (slotHead[nodes0 + j] >= 0) lref[atomicAdd(&lcnt, 1)] = nodes0 + j;
        __syncthreads();
        if (tid == 0) lbase2 = atomicAdd(nodeCnt, lcnt);
        __syncthreads();
        for (int j = tid; j < lcnt; j += 256) nodeList[lbase2 + j] = lref[j];
    }
}

// ========== gatherU v9: one 16-lane group per (r, node); write SINGLE Ud row; r==0 fills slotUidx ==========
// grid 16384 x 256: gid = bid*16+g16; r = gid>>15; i = gid&32767 indexes nodeList.
__global__ __launch_bounds__(256, 8) void gatherU(
    const int* __restrict__ nodeCnt, const int* __restrict__ nodeList,
    const int* __restrict__ slotHead, const int* __restrict__ slotNext,
    int* __restrict__ slotUidx,
    const uint* __restrict__ csr, const uint* __restrict__ pay4,
    const int* __restrict__ adj_rows, const int* __restrict__ adj_cols, const float* __restrict__ adj_vals,
    const uint* __restrict__ ovfcnt, const uint* __restrict__ ovflist,
    const ushort* __restrict__ emb16, ushort* __restrict__ Ud)
{
    const int tid = threadIdx.x, bid = blockIdx.x;
    const int g16 = tid >> 4, l16 = tid & 15;
    const int gid = bid * 16 + g16;
    const int r = gid >> 15;
    const int i = gid & 32767;
    if (i >= *nodeCnt) return;                    // uniform within the 16-lane group
    const int n = nodeList[i];

    // r==0 groups record the Ud row index for every slot referencing n
    if (r == 0 && l16 == 0) {
        int sl = slotHead[n];
        while (sl >= 0) { slotUidx[sl] = i; sl = slotNext[sl]; }
    }

    uint cd = csr[r * NN + n];
    uint s = cd >> 11;
    int deg = (int)(cd & 2047u);

    uint pv = 0;
    if (l16 < deg) pv = pay4[s + l16];            // coalesced 64B per group

    float a[8] = {0.f,0.f,0.f,0.f,0.f,0.f,0.f,0.f};
    const int dmain = deg < 16 ? deg : 16;
    for (int i0 = 0; i0 < dmain; i0 += 4) {
        const int m = dmain - i0;                 // 1..4, uniform per group
        uint p0 = __shfl(pv, i0 + 0, 16);
        uint p1 = __shfl(pv, i0 + 1, 16);
        uint p2 = __shfl(pv, i0 + 2, 16);
        uint p3 = __shfl(pv, i0 + 3, 16);
        f16x8 e0, e1, e2, e3;
        e0 = *(const f16x8*)(emb16 + (size_t)(p0 >> 16) * 128 + l16 * 8);
        if (m > 1) e1 = *(const f16x8*)(emb16 + (size_t)(p1 >> 16) * 128 + l16 * 8);
        if (m > 2) e2 = *(const f16x8*)(emb16 + (size_t)(p2 >> 16) * 128 + l16 * 8);
        if (m > 3) e3 = *(const f16x8*)(emb16 + (size_t)(p3 >> 16) * 128 + l16 * 8);
        {
            float v = (float)__builtin_bit_cast(_Float16, (ushort)(p0 & 0xFFFFu));
            #pragma unroll
            for (int q = 0; q < 8; q++) a[q] = fmaf(v, (float)e0[q], a[q]);
        }
        if (m > 1) {
            float v = (float)__builtin_bit_cast(_Float16, (ushort)(p1 & 0xFFFFu));
            #pragma unroll
            for (int q = 0; q < 8; q++) a[q] = fmaf(v, (float)e1[q], a[q]);
        }
        if (m > 2) {
            float v = (float)__builtin_bit_cast(_Float16, (ushort)(p2 & 0xFFFFu));
            #pragma unroll
            for (int q = 0; q < 8; q++) a[q] = fmaf(v, (float)e2[q], a[q]);
        }
        if (m > 3) {
            float v = (float)__builtin_bit_cast(_Float16, (ushort)(p3 & 0xFFFFu));
            #pragma unroll
            for (int q = 0; q < 8; q++) a[q] = fmaf(v, (float)e3[q], a[q]);
        }
    }
    for (int j = 16; j < deg; j++) {              // tail (P ~ 1e-9, correctness only)
        uint p = pay4[s + j];
        float v = (float)__builtin_bit_cast(_Float16, (ushort)(p & 0xFFFFu));
        f16x8 em = *(const f16x8*)(emb16 + (size_t)(p >> 16) * 128 + l16 * 8);
        #pragma unroll
        for (int q = 0; q < 8; q++) a[q] = fmaf(v, (float)em[q], a[q]);
    }
    // overflow insurance (novf == 0 in practice)
    uint novf = *ovfcnt; if (novf > OVFCAP) novf = OVFCAP;
    for (uint o = 0; o < novf; o++) {
        uint e = ovflist[o];
        if ((int)(e / EE) == r && adj_rows[e] == n) {
            float v = adj_vals[e];
            f16x8 em = *(const f16x8*)(emb16 + (size_t)adj_cols[e] * 128 + l16 * 8);
            #pragma unroll
            for (int q = 0; q < 8; q++) a[q] = fmaf(v, (float)em[q], a[q]);
        }
    }
    f16x8 uu;
    #pragma unroll
    for (int q = 0; q < 8; q++) uu[q] = (_Float16)a[q];
    *(f16x8*)(Ud + (((size_t)r << 15) + i) * 128 + l16 * 8) = uu;   // single row write
}

// =================== gemm v2: rounds 8-16 pipeline + slotUidx-indirect U reads ===================
__global__ __launch_bounds__(256) void gemm(
    const float* __restrict__ head_e, const float* __restrict__ tail_e,
    const int* __restrict__ slotUidx,
    const ushort* __restrict__ Ud, const ushort* __restrict__ Wfrag,
    float* __restrict__ out)
{
    __shared__ char sA[3][16384];
    __shared__ int  sIdx[64];
    const int tid = threadIdx.x, bid = blockIdx.x;
    const int w = tid >> 6, l = tid & 63;
    const int lr = l & 15, kq = l >> 4;
    const int nfg0 = w * 2;

    f32x4 acc[4][2];
    #pragma unroll
    for (int a = 0; a < 4; a++)
        #pragma unroll
        for (int b = 0; b < 2; b++) acc[a][b] = (f32x4){0.f, 0.f, 0.f, 0.f};

    if (tid < 64) sIdx[tid] = slotUidx[bid * 64 + tid];

    const float* S = (bid < 256) ? head_e + (size_t)bid * 64 * 128
                                 : tail_e + (size_t)(bid - 256) * 64 * 128;
    #pragma unroll
    for (int i = 0; i < 4; i++) {
        int c = i * 256 + tid;
        int row = c >> 4;
        int k8 = (c & 15) * 8;
        float4 v0 = *(const float4*)(S + (size_t)row * 128 + k8);
        float4 v1 = *(const float4*)(S + (size_t)row * 128 + k8 + 4);
        float xs[8] = {v0.x, v0.y, v0.z, v0.w, v1.x, v1.y, v1.z, v1.w};
        f16x8 h, lo;
        #pragma unroll
        for (int j = 0; j < 8; j++) {
            _Float16 hh = (_Float16)xs[j];
            h[j] = hh;
            lo[j] = (_Float16)(xs[j] - (float)hh);
        }
        int off = row * 256 + ((k8 * 2) ^ ((row & 7) << 4));
        *(f16x8*)(sA[0] + off) = h;
        *(f16x8*)(sA[1] + off) = lo;
    }
    __syncthreads();

    float4 pf0, pf1, pf2, pf3;

    #define STAGE(rr) {                                                         \
        const char* gp = (const char*)Ud + (((size_t)(rr)) << 15) * 256;        \
        _Pragma("unroll")                                                       \
        for (int ii = 0; ii < 4; ii++) {                                        \
            int c = ii * 256 + tid;                                             \
            size_t off = (size_t)sIdx[c >> 4] * 256 + (c & 15) * 16;            \
            float4 v = *(const float4*)(gp + off);                              \
            if (ii == 0) pf0 = v; else if (ii == 1) pf1 = v;                    \
            else if (ii == 2) pf2 = v; else pf3 = v;                            \
        }                                                                       \
    }
    #define WRITE(buf) {                                                        \
        _Pragma("unroll")                                                       \
        for (int i = 0; i < 4; i++) {                                           \
            int c = i * 256 + tid;                                              \
            int row = c >> 4, cc = c & 15;                                      \
            int off = row * 256 + ((cc * 16) ^ ((row & 7) << 4));               \
            *(float4*)(sA[buf] + off) = (i==0)?pf0:(i==1)?pf1:(i==2)?pf2:pf3;   \
        }                                                                       \
    }

    STAGE(0);
    {
        const ushort* Wb = Wfrag + (size_t)(8 * 2) * 16384;
        #pragma unroll
        for (int ks = 0; ks < 4; ks++) {
            int kb = ks * 64 + kq * 16;
            f16x8 ah[4], al[4], bh[2], bl[2];
            #pragma unroll
            for (int nf = 0; nf < 2; nf++) {
                size_t bo = (size_t)(((nfg0 + nf) * 4 + ks) * 64 + l) * 8;
                bh[nf] = *(const f16x8*)(Wb + bo);
                bl[nf] = *(const f16x8*)(Wb + 16384 + bo);
            }
            #pragma unroll
            for (int mf = 0; mf < 4; mf++) {
                int row = mf * 16 + lr;
                int off = row * 256 + (kb ^ ((row & 7) << 4));
                ah[mf] = *(const f16x8*)(sA[0] + off);
                al[mf] = *(const f16x8*)(sA[1] + off);
            }
            #pragma unroll
            for (int mf = 0; mf < 4; mf++)
                #pragma unroll
                for (int nf = 0; nf < 2; nf++) {
                    acc[mf][nf] = __builtin_amdgcn_mfma_f32_16x16x32_f16(ah[mf], bh[nf], acc[mf][nf], 0, 0, 0);
                    acc[mf][nf] = __builtin_amdgcn_mfma_f32_16x16x32_f16(ah[mf], bl[nf], acc[mf][nf], 0, 0, 0);
                    acc[mf][nf] = __builtin_amdgcn_mfma_f32_16x16x32_f16(al[mf], bh[nf], acc[mf][nf], 0, 0, 0);
                }
        }
    }
    WRITE(2);
    __syncthreads();

    for (int r = 0; r < RR; r++) {
        if (r < 7) STAGE(r + 1);
        const ushort* Wb = Wfrag + (size_t)(r * 2) * 16384;
        const char* bufp = sA[(r + 2) % 3];
        #pragma unroll
        for (int ks = 0; ks < 4; ks++) {
            int kb = ks * 64 + kq * 16;
            f16x8 av[4], bh[2], bl[2];
            #pragma unroll
            for (int nf = 0; nf < 2; nf++) {
                size_t bo = (size_t)(((nfg0 + nf) * 4 + ks) * 64 + l) * 8;
                bh[nf] = *(const f16x8*)(Wb + bo);
                bl[nf] = *(const f16x8*)(Wb + 16384 + bo);
            }
            #pragma unroll
            for (int mf = 0; mf < 4; mf++) {
                int row = mf * 16 + lr;
                av[mf] = *(const f16x8*)(bufp + row * 256 + (kb ^ ((row & 7) << 4)));
            }
            #pragma unroll
            for (int mf = 0; mf < 4; mf++)
                #pragma unroll
                for (int nf = 0; nf < 2; nf++) {
                    acc[mf][nf] = __builtin_amdgcn_mfma_f32_16x16x32_f16(av[mf], bh[nf], acc[mf][nf], 0, 0, 0);
                    acc[mf][nf] = __builtin_amdgcn_mfma_f32_16x16x32_f16(av[mf], bl[nf], acc[mf][nf], 0, 0, 0);
                }
        }
        if (r < 7) {
            WRITE(r % 3);
            __syncthreads();
        }
    }

    #pragma unroll
    for (int mf = 0; mf < 4; mf++)
        #pragma unroll
        for (int j = 0; j < 4; j++) {
            int lrow = mf * 16 + kq * 4 + j;
            size_t slot = (size_t)bid * 64 + lrow;
            #pragma unroll
            for (int nf = 0; nf < 2; nf++) {
                int col = (nfg0 + nf) * 16 + lr;
                float x = acc[mf][nf][j];
                out[slot * 128 + col] = 1.f / (1.f + __expf(-x));
            }
        }
    #undef STAGE
    #undef WRITE
}

extern "C" void kernel_launch(void* const* d_in, const int* in_sizes, int n_in,
                              void* d_out, int out_size, void* d_ws, size_t ws_size,
                              hipStream_t stream)
{
    const float* embeddings = (const float*)d_in[0];
    const int*   head_idx   = (const int*)d_in[1];
    const float* head_e     = (const float*)d_in[2];
    const int*   tail_idx   = (const int*)d_in[3];
    const float* tail_e     = (const float*)d_in[4];
    const int*   adj_rows   = (const int*)d_in[5];
    const int*   adj_cols   = (const int*)d_in[6];
    const float* adj_vals   = (const float*)d_in[7];
    const float* rel_k      = (const float*)d_in[8];
    const float* self_k     = (const float*)d_in[9];
    float* out = (float*)d_out;

    // workspace layout (~102 MB)
    char* ws = (char*)d_ws;
    uint*   cursor   = (uint*)ws;                     //   3,136 B
    uint*   ovfcnt   = (uint*)(ws + 3136);            //       4 B
    int*    nodeCnt  = (int*)(ws + 3140);             //       4 B
    uint*   ovflist  = (uint*)(ws + 3144);            //   4,096 B
    int*    slotHead = (int*)(ws + 8192);             //     200,000 B
    int*    slotNext = (int*)(ws + 208192);           //     131,072 B
    int*    slotUidx = (int*)(ws + 339264);           //     131,072 B
    ushort* Wfrag    = (ushort*)(ws + 470336);        //     589,824 B
    ushort* emb16    = (ushort*)(ws + 1060160);       //  12,800,000 B
    uint*   csr      = (uint*)(ws + 13860160);        //   1,600,000 B
    uint*   pay4     = (uint*)(ws + 15460160);        //   6,422,528 B
    uint2*  gpart    = (uint2*)(ws + 21882688);       //  12,845,056 B
    ushort* Ud       = (ushort*)(ws + 34727744);      //  67,108,864 B
    int*    nodeList = (int*)(ws + 101836608);        //     131,072 B

    hipMemsetAsync(cursor, 0, 3144, stream);          // cursor + ovfcnt + nodeCnt
    hipMemsetAsync(slotHead, 0xFF, (size_t)NN * 4, stream);

    scatterK<<<800, 256, 0, stream>>>(embeddings, rel_k, self_k,
                                      head_idx, tail_idx,
                                      adj_rows, adj_cols, adj_vals,
                                      cursor, ovfcnt, ovflist, gpart,
                                      slotHead, slotNext, emb16, Wfrag);

    groupK<<<784, 256, 0, stream>>>(cursor, gpart, slotHead, pay4, csr,
                                    nodeCnt, nodeList);

    gatherU<<<16384, 256, 0, stream>>>(nodeCnt, nodeList, slotHead, slotNext,
                                       slotUidx, csr, pay4,
                                       adj_rows, adj_cols, adj_vals,
                                       ovfcnt, ovflist, emb16, Ud);

    gemm<<<512, 256, 0, stream>>>(head_e, tail_e, slotUidx, Ud, Wfrag, out);
}

// Round 18
// 91.043 us; speedup vs baseline: 1.0220x; 1.0220x over previous
//
#include <hip/hip_runtime.h>
#include <math.h>

#define NN 50000
#define RR 8
#define EE 100000
#define BB 16384
#define ET 800000
#define NB 98                 // coarse buckets per relation (512 nodes each)
#define CAP 2048              // region stride in edges (stored cnt <= 2047)
#define OVFCAP 1024

typedef unsigned int uint;
typedef unsigned short ushort;
typedef __attribute__((ext_vector_type(4))) float f32x4;
typedef _Float16 f16x8 __attribute__((ext_vector_type(8)));

// pay4[pos]: (col<<16 | val_fp16), grouped by (r, node) per CSR.
// csr[r*NN+n] = (absStart << 11) | deg. nodeList[0..nodeCnt): referenced nodes (dedup).
// slotHead[n]/slotNext[slot]: node -> slots inverse lists.
// Wfrag: [slot(9)][hi/lo][nfg(8)][ks(4)][lane(64)][8 f16]. U16: 8 planes [32768][128] fp16.

// ========== scatterK: round 12 + slot inverse-lists (measured cheap) ==========
__global__ __launch_bounds__(256) void scatterK(
    const float* __restrict__ emb, const float* __restrict__ rel_k, const float* __restrict__ self_k,
    const int* __restrict__ head_idx, const int* __restrict__ tail_idx,
    const int* __restrict__ adj_rows, const int* __restrict__ adj_cols, const float* __restrict__ adj_vals,
    uint* __restrict__ cursor, uint* __restrict__ ovfcnt, uint* __restrict__ ovflist,
    uint2* __restrict__ gpart, int* __restrict__ slotHead, int* __restrict__ slotNext,
    ushort* __restrict__ emb16, ushort* __restrict__ Wfrag)
{
    __shared__ int  srow[2000];
    __shared__ int  hist[NB];
    __shared__ uint lbase[NB];
    const int tid = threadIdx.x, bid = blockIdx.x;

    // ---- node->slot inverse lists: 32K atomicExch total ----
    {
        int g = bid * 256 + tid;
        if (g < 2 * BB) {
            int n = (g < BB) ? head_idx[g] : tail_idx[g - BB];
            slotNext[g] = atomicExch(&slotHead[n], g);
        }
    }

    if (bid < 400) {
        const int r  = bid / 50;
        const int e0 = bid * 2000;
        for (int k = tid; k < NB; k += 256) hist[k] = 0;
        __syncthreads();
        for (int i = tid; i < 2000; i += 256) {
            int n = adj_rows[e0 + i];
            srow[i] = n;
            atomicAdd(&hist[n >> 9], 1);
        }
        __syncthreads();
        if (tid < NB) {
            int h = hist[tid];
            lbase[tid] = h ? atomicAdd(&cursor[r * NB + tid], (uint)h) : 0u;
        }
        __syncthreads();
        for (int i = tid; i < 2000; i += 256) {
            int n = srow[i];
            int c = n >> 9;
            uint prel = atomicAdd(&lbase[c], 1u);
            int e = e0 + i;
            ushort v16 = __builtin_bit_cast(ushort, (_Float16)adj_vals[e]);
            uint pay = ((uint)adj_cols[e] << 16) | (uint)v16;
            if (prel < (uint)(CAP - 1)) {
                gpart[(size_t)(r * NB + c) * CAP + prel] = make_uint2(pay, (uint)n);
            } else {
                uint o = atomicAdd(ovfcnt, 1u);
                if (o < OVFCAP) ovflist[o] = (uint)e;
            }
        }
    } else if (bid < 791) {
        int b = bid - 400;
        #pragma unroll
        for (int i = 0; i < 16; i++) {
            int c = i * 256 + tid;
            int row = b * 128 + (c >> 5);
            if (row < NN) {
                int k4 = (c & 31) * 4;
                float4 v = *(const float4*)(emb + (size_t)row * 128 + k4);
                _Float16 h4[4] = {(_Float16)v.x, (_Float16)v.y, (_Float16)v.z, (_Float16)v.w};
                *(ulonglong1*)(emb16 + (size_t)row * 128 + k4) = *(ulonglong1*)h4;
            }
        }
    } else {
        int r = bid - 791;
        const float* src = (r < RR) ? rel_k + (size_t)r * 128 * 128 : self_k;
        #pragma unroll
        for (int q = 0; q < 8; q++) {
            int ls = q * 256 + tid;
            int nfg = ls >> 8, ks = (ls >> 6) & 3, lane = ls & 63;
            int n = nfg * 16 + (lane & 15);
            int k0 = ks * 32 + (lane >> 4) * 8;
            f16x8 hi, lo;
            #pragma unroll
            for (int j = 0; j < 8; j++) {
                float x = src[(size_t)(k0 + j) * 128 + n];
                _Float16 h = (_Float16)x;
                hi[j] = h;
                lo[j] = (_Float16)(x - (float)h);
            }
            size_t bo = (size_t)(r * 2) * 16384 + (size_t)(nfg * 4 + ks) * 512 + (size_t)lane * 8;
            *(f16x8*)(Wfrag + bo)         = hi;
            *(f16x8*)(Wfrag + 16384 + bo) = lo;
        }
    }
}

// ========== groupK: round 12 counting-sort + referenced-node compaction (r==0 blocks) ==========
__global__ __launch_bounds__(256) void groupK(
    const uint* __restrict__ cursor, const uint2* __restrict__ gpart,
    const int* __restrict__ slotHead,
    uint* __restrict__ pay4, uint* __restrict__ csr,
    int* __restrict__ nodeCnt, int* __restrict__ nodeList)
{
    __shared__ ushort skey[CAP];
    __shared__ uint   spin[CAP];
    __shared__ uint   ssort[CAP];
    __shared__ int    cnt2[512];
    __shared__ int    sa[512], sb[512];
    __shared__ int    cur2[512];
    __shared__ int    lref[512];
    __shared__ int    lcnt, lbase2;
    const int tid = threadIdx.x, rc = blockIdx.x;
    const int c = rc % NB, r = rc / NB;
    const int nodes0 = c * 512;
    const int nnodes = (c == NB - 1) ? (NN - nodes0) : 512;
    uint cntv = cursor[rc]; if (cntv > (uint)(CAP - 1)) cntv = CAP - 1;
    const int cnt = (int)cntv;

    if (tid == 0) lcnt = 0;
    for (int k = tid; k < 512; k += 256) cnt2[k] = 0;
    __syncthreads();
    for (int i = tid; i < cnt; i += 256) {
        uint2 p = gpart[(size_t)rc * CAP + i];
        int key = (int)p.y - nodes0;
        skey[i] = (ushort)key;
        spin[i] = p.x;
        atomicAdd(&cnt2[key], 1);
    }
    __syncthreads();
    for (int k = tid; k < 512; k += 256) sa[k] = cnt2[k];
    __syncthreads();
    int* src = sa; int* dst = sb;
    for (int d = 1; d < 512; d <<= 1) {
        for (int k = tid; k < 512; k += 256)
            dst[k] = src[k] + (k >= d ? src[k - d] : 0);
        __syncthreads();
        int* t = src; src = dst; dst = t;
    }
    for (int k = tid; k < 512; k += 256) cur2[k] = k ? src[k - 1] : 0;
    __syncthreads();
    for (int i = tid; i < cnt; i += 256) {
        int p = atomicAdd(&cur2[skey[i]], 1);
        ssort[p] = spin[i];
    }
    __syncthreads();
    for (int i = tid; i < cnt; i += 256)
        pay4[(size_t)rc * CAP + i] = ssort[i];
    for (int j = tid; j < nnodes; j += 256) {
        uint start = (uint)rc * CAP + (uint)(j ? src[j - 1] : 0);
        csr[r * NN + nodes0 + j] = (start << 11) | (uint)cnt2[j];
    }

    // ---- referenced-node compaction (only relation-0 blocks; node set is r-independent) ----
    if (r == 0) {
        for (int j = tid; j < nnodes; j += 256)
            if (slotHead[nodes0 + j] >= 0) lref[atomicAdd(&lcnt, 1)] = nodes0 + j;
        __syncthreads();
        if (tid == 0) lbase2 = atomicAdd(nodeCnt, lcnt);
        __syncthreads();
        for (int j = tid; j < lcnt; j += 256) nodeList[lbase2 + j] = lref[j];
    }
}

// ========== gatherU v8: one 16-lane group per (r, referenced node); MLP-4; write all slots ==========
// grid 16384 x 256: gid = bid*16+g16; r = gid>>15; i = gid&32767 indexes nodeList.
__global__ __launch_bounds__(256, 8) void gatherU(
    const int* __restrict__ nodeCnt, const int* __restrict__ nodeList,
    const int* __restrict__ slotHead, const int* __restrict__ slotNext,
    const uint* __restrict__ csr, const uint* __restrict__ pay4,
    const int* __restrict__ adj_rows, const int* __restrict__ adj_cols, const float* __restrict__ adj_vals,
    const uint* __restrict__ ovfcnt, const uint* __restrict__ ovflist,
    const ushort* __restrict__ emb16, ushort* __restrict__ U16)
{
    const int tid = threadIdx.x, bid = blockIdx.x;
    const int g16 = tid >> 4, l16 = tid & 15;
    const int gid = bid * 16 + g16;
    const int r = gid >> 15;
    const int i = gid & 32767;
    if (i >= *nodeCnt) return;                    // uniform within the 16-lane group
    const int n = nodeList[i];

    uint cd = csr[r * NN + n];
    uint s = cd >> 11;
    int deg = (int)(cd & 2047u);

    uint pv = 0;
    if (l16 < deg) pv = pay4[s + l16];            // coalesced 64B per group

    float a[8] = {0.f,0.f,0.f,0.f,0.f,0.f,0.f,0.f};
    const int dmain = deg < 16 ? deg : 16;
    for (int i0 = 0; i0 < dmain; i0 += 4) {
        const int m = dmain - i0;                 // 1..4, uniform per group
        uint p0 = __shfl(pv, i0 + 0, 16);
        uint p1 = __shfl(pv, i0 + 1, 16);
        uint p2 = __shfl(pv, i0 + 2, 16);
        uint p3 = __shfl(pv, i0 + 3, 16);
        f16x8 e0, e1, e2, e3;
        e0 = *(const f16x8*)(emb16 + (size_t)(p0 >> 16) * 128 + l16 * 8);
        if (m > 1) e1 = *(const f16x8*)(emb16 + (size_t)(p1 >> 16) * 128 + l16 * 8);
        if (m > 2) e2 = *(const f16x8*)(emb16 + (size_t)(p2 >> 16) * 128 + l16 * 8);
        if (m > 3) e3 = *(const f16x8*)(emb16 + (size_t)(p3 >> 16) * 128 + l16 * 8);
        {
            float v = (float)__builtin_bit_cast(_Float16, (ushort)(p0 & 0xFFFFu));
            #pragma unroll
            for (int q = 0; q < 8; q++) a[q] = fmaf(v, (float)e0[q], a[q]);
        }
        if (m > 1) {
            float v = (float)__builtin_bit_cast(_Float16, (ushort)(p1 & 0xFFFFu));
            #pragma unroll
            for (int q = 0; q < 8; q++) a[q] = fmaf(v, (float)e1[q], a[q]);
        }
        if (m > 2) {
            float v = (float)__builtin_bit_cast(_Float16, (ushort)(p2 & 0xFFFFu));
            #pragma unroll
            for (int q = 0; q < 8; q++) a[q] = fmaf(v, (float)e2[q], a[q]);
        }
        if (m > 3) {
            float v = (float)__builtin_bit_cast(_Float16, (ushort)(p3 & 0xFFFFu));
            #pragma unroll
            for (int q = 0; q < 8; q++) a[q] = fmaf(v, (float)e3[q], a[q]);
        }
    }
    for (int j = 16; j < deg; j++) {              // tail (P ~ 1e-9, correctness only)
        uint p = pay4[s + j];
        float v = (float)__builtin_bit_cast(_Float16, (ushort)(p & 0xFFFFu));
        f16x8 em = *(const f16x8*)(emb16 + (size_t)(p >> 16) * 128 + l16 * 8);
        #pragma unroll
        for (int q = 0; q < 8; q++) a[q] = fmaf(v, (float)em[q], a[q]);
    }
    // overflow insurance (novf == 0 in practice)
    uint novf = *ovfcnt; if (novf > OVFCAP) novf = OVFCAP;
    for (uint o = 0; o < novf; o++) {
        uint e = ovflist[o];
        if ((int)(e / EE) == r && adj_rows[e] == n) {
            float v = adj_vals[e];
            f16x8 em = *(const f16x8*)(emb16 + (size_t)adj_cols[e] * 128 + l16 * 8);
            #pragma unroll
            for (int q = 0; q < 8; q++) a[q] = fmaf(v, (float)em[q], a[q]);
        }
    }
    f16x8 uu;
    #pragma unroll
    for (int q = 0; q < 8; q++) uu[q] = (_Float16)a[q];
    // write to every slot referencing node n (avg 1.36; 256B aligned contiguous rows)
    int sl = slotHead[n];
    while (sl >= 0) {
        *(f16x8*)(U16 + ((size_t)r * 32768 + sl) * 128 + l16 * 8) = uu;
        sl = slotNext[sl];
    }
}

// =================== gemm: verbatim rounds 8-12 (passing) ===================
__global__ __launch_bounds__(256) void gemm(
    const float* __restrict__ head_e, const float* __restrict__ tail_e,
    const ushort* __restrict__ U16, const ushort* __restrict__ Wfrag,
    float* __restrict__ out)
{
    __shared__ char sA[3][16384];
    const int tid = threadIdx.x, bid = blockIdx.x;
    const int w = tid >> 6, l = tid & 63;
    const int lr = l & 15, kq = l >> 4;
    const int nfg0 = w * 2;

    f32x4 acc[4][2];
    #pragma unroll
    for (int a = 0; a < 4; a++)
        #pragma unroll
        for (int b = 0; b < 2; b++) acc[a][b] = (f32x4){0.f, 0.f, 0.f, 0.f};

    const float* S = (bid < 256) ? head_e + (size_t)bid * 64 * 128
                                 : tail_e + (size_t)(bid - 256) * 64 * 128;
    #pragma unroll
    for (int i = 0; i < 4; i++) {
        int c = i * 256 + tid;
        int row = c >> 4;
        int k8 = (c & 15) * 8;
        float4 v0 = *(const float4*)(S + (size_t)row * 128 + k8);
        float4 v1 = *(const float4*)(S + (size_t)row * 128 + k8 + 4);
        float xs[8] = {v0.x, v0.y, v0.z, v0.w, v1.x, v1.y, v1.z, v1.w};
        f16x8 h, lo;
        #pragma unroll
        for (int j = 0; j < 8; j++) {
            _Float16 hh = (_Float16)xs[j];
            h[j] = hh;
            lo[j] = (_Float16)(xs[j] - (float)hh);
        }
        int off = row * 256 + ((k8 * 2) ^ ((row & 7) << 4));
        *(f16x8*)(sA[0] + off) = h;
        *(f16x8*)(sA[1] + off) = lo;
    }
    __syncthreads();

    float4 pf0, pf1, pf2, pf3;
    const char* Ub = (const char*)U16 + (size_t)bid * 64 * 256;

    #define STAGE(r) {                                                          \
        const char* gp = Ub + (size_t)(r) * 32768 * 256;                        \
        pf0 = *(const float4*)(gp + (0 * 256 + tid) * 16);                      \
        pf1 = *(const float4*)(gp + (1 * 256 + tid) * 16);                      \
        pf2 = *(const float4*)(gp + (2 * 256 + tid) * 16);                      \
        pf3 = *(const float4*)(gp + (3 * 256 + tid) * 16);                      \
    }
    #define WRITE(buf) {                                                        \
        _Pragma("unroll")                                                       \
        for (int i = 0; i < 4; i++) {                                           \
            int c = i * 256 + tid;                                              \
            int row = c >> 4, cc = c & 15;                                      \
            int off = row * 256 + ((cc * 16) ^ ((row & 7) << 4));               \
            *(float4*)(sA[buf] + off) = (i==0)?pf0:(i==1)?pf1:(i==2)?pf2:pf3;   \
        }                                                                       \
    }

    STAGE(0);
    {
        const ushort* Wb = Wfrag + (size_t)(8 * 2) * 16384;
        #pragma unroll
        for (int ks = 0; ks < 4; ks++) {
            int kb = ks * 64 + kq * 16;
            f16x8 ah[4], al[4], bh[2], bl[2];
            #pragma unroll
            for (int nf = 0; nf < 2; nf++) {
                size_t bo = (size_t)(((nfg0 + nf) * 4 + ks) * 64 + l) * 8;
                bh[nf] = *(const f16x8*)(Wb + bo);
                bl[nf] = *(const f16x8*)(Wb + 16384 + bo);
            }
            #pragma unroll
            for (int mf = 0; mf < 4; mf++) {
                int row = mf * 16 + lr;
                int off = row * 256 + (kb ^ ((row & 7) << 4));
                ah[mf] = *(const f16x8*)(sA[0] + off);
                al[mf] = *(const f16x8*)(sA[1] + off);
            }
            #pragma unroll
            for (int mf = 0; mf < 4; mf++)
                #pragma unroll
                for (int nf = 0; nf < 2; nf++) {
                    acc[mf][nf] = __builtin_amdgcn_mfma_f32_16x16x32_f16(ah[mf], bh[nf], acc[mf][nf], 0, 0, 0);
                    acc[mf][nf] = __builtin_amdgcn_mfma_f32_16x16x32_f16(ah[mf], bl[nf], acc[mf][nf], 0, 0, 0);
                    acc[mf][nf] = __builtin_amdgcn_mfma_f32_16x16x32_f16(al[mf], bh[nf], acc[mf][nf], 0, 0, 0);
                }
        }
    }
    WRITE(2);
    __syncthreads();

    for (int r = 0; r < RR; r++) {
        if (r < 7) STAGE(r + 1);
        const ushort* Wb = Wfrag + (size_t)(r * 2) * 16384;
        const char* bufp = sA[(r + 2) % 3];
        #pragma unroll
        for (int ks = 0; ks < 4; ks++) {
            int kb = ks * 64 + kq * 16;
            f16x8 av[4], bh[2], bl[2];
            #pragma unroll
            for (int nf = 0; nf < 2; nf++) {
                size_t bo = (size_t)(((nfg0 + nf) * 4 + ks) * 64 + l) * 8;
                bh[nf] = *(const f16x8*)(Wb + bo);
                bl[nf] = *(const f16x8*)(Wb + 16384 + bo);
            }
            #pragma unroll
            for (int mf = 0; mf < 4; mf++) {
                int row = mf * 16 + lr;
                av[mf] = *(const f16x8*)(bufp + row * 256 + (kb ^ ((row & 7) << 4)));
            }
            #pragma unroll
            for (int mf = 0; mf < 4; mf++)
                #pragma unroll
                for (int nf = 0; nf < 2; nf++) {
                    acc[mf][nf] = __builtin_amdgcn_mfma_f32_16x16x32_f16(av[mf], bh[nf], acc[mf][nf], 0, 0, 0);
                    acc[mf][nf] = __builtin_amdgcn_mfma_f32_16x16x32_f16(av[mf], bl[nf], acc[mf][nf], 0, 0, 0);
                }
        }
        if (r < 7) {
            WRITE(r % 3);
            __syncthreads();
        }
    }

    #pragma unroll
    for (int mf = 0; mf < 4; mf++)
        #pragma unroll
        for (int j = 0; j < 4; j++) {
            int lrow = mf * 16 + kq * 4 + j;
            size_t slot = (size_t)bid * 64 + lrow;
            #pragma unroll
            for (int nf = 0; nf < 2; nf++) {
                int col = (nfg0 + nf) * 16 + lr;
                float x = acc[mf][nf][j];
                out[slot * 128 + col] = 1.f / (1.f + __expf(-x));
            }
        }
    #undef STAGE
    #undef WRITE
}

extern "C" void kernel_launch(void* const* d_in, const int* in_sizes, int n_in,
                              void* d_out, int out_size, void* d_ws, size_t ws_size,
                              hipStream_t stream)
{
    const float* embeddings = (const float*)d_in[0];
    const int*   head_idx   = (const int*)d_in[1];
    const float* head_e     = (const float*)d_in[2];
    const int*   tail_idx   = (const int*)d_in[3];
    const float* tail_e     = (const float*)d_in[4];
    const int*   adj_rows   = (const int*)d_in[5];
    const int*   adj_cols   = (const int*)d_in[6];
    const float* adj_vals   = (const float*)d_in[7];
    const float* rel_k      = (const float*)d_in[8];
    const float* self_k     = (const float*)d_in[9];
    float* out = (float*)d_out;

    // workspace layout (~101.9 MB)
    char* ws = (char*)d_ws;
    uint*   cursor   = (uint*)ws;                     //   3,136 B
    uint*   ovfcnt   = (uint*)(ws + 3136);            //       4 B
    int*    nodeCnt  = (int*)(ws + 3140);             //       4 B
    uint*   ovflist  = (uint*)(ws + 3144);            //   4,096 B
    int*    slotHead = (int*)(ws + 8192);             //     200,000 B
    int*    slotNext = (int*)(ws + 208192);           //     131,072 B
    ushort* Wfrag    = (ushort*)(ws + 339456);        //     589,824 B
    ushort* emb16    = (ushort*)(ws + 929280);        //  12,800,000 B
    uint*   csr      = (uint*)(ws + 13729280);        //   1,600,000 B
    uint*   pay4     = (uint*)(ws + 15329280);        //   6,422,528 B
    uint2*  gpart    = (uint2*)(ws + 21751808);       //  12,845,056 B
    ushort* U16      = (ushort*)(ws + 34596864);      //  67,108,864 B
    int*    nodeList = (int*)(ws + 101705728);        //     131,072 B

    hipMemsetAsync(cursor, 0, 3144, stream);          // cursor + ovfcnt + nodeCnt
    hipMemsetAsync(slotHead, 0xFF, (size_t)NN * 4, stream);

    scatterK<<<800, 256, 0, stream>>>(embeddings, rel_k, self_k,
                                      head_idx, tail_idx,
                                      adj_rows, adj_cols, adj_vals,
                                      cursor, ovfcnt, ovflist, gpart,
                                      slotHead, slotNext, emb16, Wfrag);

    groupK<<<784, 256, 0, stream>>>(cursor, gpart, slotHead, pay4, csr,
                                    nodeCnt, nodeList);

    gatherU<<<16384, 256, 0, stream>>>(nodeCnt, nodeList, slotHead, slotNext,
                                       csr, pay4,
                                       adj_rows, adj_cols, adj_vals,
                                       ovfcnt, ovflist, emb16, U16);

    gemm<<<512, 256, 0, stream>>>(head_e, tail_e, U16, Wfrag, out);
}